// Round 6
// baseline (431.711 us; speedup 1.0000x reference)
//
#include <hip/hip_runtime.h>
#include <cmath>

#define BB 8
#define SS 8192
#define DD 384
#define CH 64
#define NC 128
#define FB 49152   // fragment-linear block per batch

typedef _Float16 h8_t __attribute__((ext_vector_type(8)));
typedef _Float16 h4_t __attribute__((ext_vector_type(4)));
typedef float f32x4 __attribute__((ext_vector_type(4)));

#define MFMA __builtin_amdgcn_mfma_f32_16x16x32_f16

// swizzled LDS accessors
#define LDSA(row, colb) (*(const h8_t*)((const char*)As + (size_t)(row) * 768 + (((colb)) ^ ((((row)) & 7) << 4))))
#define LDSS(row, colb) (*(const h8_t*)((const char*)Ss + (size_t)(row) * 256 + (((colb)) ^ ((((row)) & 7) << 4))))

// ---------------------------------------------------------------- K1: stats
__global__ __launch_bounds__(512) void k1_stats(
    const float* __restrict__ x, const float* __restrict__ M0,
    const float* __restrict__ eta_raw, const float* __restrict__ alpha_raw,
    const float* __restrict__ gate_w, const float* __restrict__ gate_b,
    _Float16* __restrict__ XF, _Float16* __restrict__ KF,
    _Float16* __restrict__ KFF, _Float16* __restrict__ UFF,
    float* __restrict__ AB, float* __restrict__ TAB,
    float* __restrict__ SKK, _Float16* __restrict__ M0F)
{
    __shared__ _Float16 ch[CH * 392];   // 50176 B
    __shared__ float rinv[CH];
    __shared__ float kmS[DD], uS[DD];
    __shared__ float redg[8], redk[8];
    const int wg = blockIdx.x, tid = threadIdx.x;
    const int b = wg >> 7, n = wg & 127;
    const int lane = tid & 63, wid = tid >> 6;

    if (wg < 64 && tid < 288) {  // M0 -> f16 fragment-linear
        int rl = tid / 48, c = tid % 48, kd = c >> 2, q = c & 3;
        int o = wg * 6 + rl, rt = o >> 4, l15o = o & 15;
        h8_t v;
        for (int i = 0; i < 8; ++i)
            v[i] = (_Float16)M0[(size_t)o * DD + kd * 32 + q * 8 + i];
        *(h8_t*)&M0F[(size_t)(((kd * 24 + rt) * 64 + q * 16 + l15o) << 3)] = v;
    }

    const size_t chunk_off = (size_t)(b * SS + n * CH) * DD;
    const float4* __restrict__ xin = (const float4*)(x + chunk_off);
    h4_t* __restrict__ xf = (h4_t*)(XF + chunk_off);
    for (int i = tid; i < CH * DD / 4; i += 512) {
        float4 v = xin[i];
        int base = i * 4, r = base / DD, c = base % DD;
        h4_t h; h[0] = (_Float16)v.x; h[1] = (_Float16)v.y;
        h[2] = (_Float16)v.z; h[3] = (_Float16)v.w;
        *(h4_t*)&ch[r * 392 + c] = h;
        xf[i] = h;
    }
    __syncthreads();

    for (int r = wid * 8; r < wid * 8 + 8; ++r) {
        float s = 0.f;
        for (int t = 0; t < 6; ++t) {
            float v = (float)ch[r * 392 + lane + 64 * t]; s += v * v;
        }
        for (int off = 32; off; off >>= 1) s += __shfl_xor(s, off);
        if (lane == 0) rinv[r] = 1.f / fmaxf(sqrtf(s), 1e-5f);
    }
    __syncthreads();

    float gpart = 0.f, skkp = 0.f;
    for (int d = tid; d < DD; d += 512) {
        float xa = 0.f, km = 0.f;
        for (int c = 0; c < CH; ++c) {
            float v = (float)ch[c * 392 + d]; xa += v; km += v * rinv[c];
        }
        xa *= (1.f / 64.f); km *= (1.f / 64.f);
        KF[(size_t)(b * NC + n) * DD + d] = (_Float16)km;
        kmS[d] = km; uS[d] = xa - km;
        gpart += km * gate_w[d];
        skkp += km * km;
    }
    for (int off = 32; off; off >>= 1) {
        gpart += __shfl_xor(gpart, off);
        skkp += __shfl_xor(skkp, off);
    }
    if (lane == 0) { redg[wid] = gpart; redk[wid] = skkp; }
    __syncthreads();
    if (tid == 0) {
        float gsum = 0.f, ks = 0.f;
        for (int i = 0; i < 8; ++i) { gsum += redg[i]; ks += redk[i]; }
        float g = 1.f / (1.f + expf(-(gsum + gate_b[0])));
        float eta = 0.2f / (1.f + expf(-eta_raw[0]));
        float alpha = 0.5f + 0.5f / (1.f + expf(-alpha_raw[0]));
        float A = g * alpha + 1.f - g;
        float Bc = g * eta;
        AB[wg * 2 + 0] = A;
        AB[wg * 2 + 1] = Bc;
        TAB[wg] = Bc / A;
        SKK[wg] = ks;
    }
    if (tid < 96) {  // KFF / UFF fragment-linear slivers for row n
        int isU = tid >= 48, c = tid & 47;
        int kd = c >> 2, q = c & 3;
        int rt = n >> 4, l15n = n & 15;
        h8_t v;
        for (int i = 0; i < 8; ++i)
            v[i] = (_Float16)(isU ? uS[kd * 32 + q * 8 + i] : kmS[kd * 32 + q * 8 + i]);
        _Float16* dst = isU ? UFF : KFF;
        *(h8_t*)&dst[(size_t)b * FB + (((kd * 8 + rt) * 64 + q * 16 + l15n) << 3)] = v;
    }
}

// ---------------------------------------------------------------- kA: gram + v0
__global__ __launch_bounds__(256) void kA(
    const _Float16* __restrict__ KFF, const _Float16* __restrict__ UFF,
    const _Float16* __restrict__ M0F, const float* __restrict__ TAB,
    _Float16* __restrict__ GT, _Float16* __restrict__ HT,
    _Float16* __restrict__ V0T)
{
    const int tid = threadIdx.x, lane = tid & 63, w = tid >> 6;
    const int q = lane >> 4, l15 = lane & 15;
    if (blockIdx.x < 8) {
        const int b = blockIdx.x;
        for (int pass = 0; pass < 2; ++pass) {
            const _Float16* Bm = pass ? KFF : UFF;
            _Float16* Out = pass ? HT : GT;
            f32x4 acc[2][8];
            for (int mt = 0; mt < 2; ++mt)
                for (int nt = 0; nt < 8; ++nt) acc[mt][nt] = (f32x4){0.f, 0.f, 0.f, 0.f};
            for (int kd = 0; kd < 12; ++kd) {
                h8_t af[2];
                for (int mt = 0; mt < 2; ++mt)
                    af[mt] = *(const h8_t*)&KFF[(size_t)b * FB + (((kd * 8 + w * 2 + mt) * 64 + lane) << 3)];
                h8_t bf[8];
                for (int nt = 0; nt < 8; ++nt)
                    bf[nt] = *(const h8_t*)&Bm[(size_t)b * FB + (((kd * 8 + nt) * 64 + lane) << 3)];
                for (int mt = 0; mt < 2; ++mt)
                    for (int nt = 0; nt < 8; ++nt)
                        acc[mt][nt] = MFMA(af[mt], bf[nt], acc[mt][nt], 0, 0, 0);
            }
            for (int mt = 0; mt < 2; ++mt)
                for (int nt = 0; nt < 8; ++nt)
                    for (int r = 0; r < 4; ++r) {
                        int j = w * 32 + mt * 16 + q * 4 + r;
                        int nn = nt * 16 + l15;
                        float v = (j < nn) ? TAB[b * NC + j] * acc[mt][nt][r] : 0.f;
                        Out[((size_t)b * NC + nn) * NC + j] = (_Float16)v;
                    }
        }
    } else {
        const int idx = blockIdx.x - 8;
        const int b = idx / 3, ob = idx % 3;
        f32x4 acc[2][8];
        for (int mt = 0; mt < 2; ++mt)
            for (int ot = 0; ot < 8; ++ot) acc[mt][ot] = (f32x4){0.f, 0.f, 0.f, 0.f};
        for (int kd = 0; kd < 12; ++kd) {
            h8_t af[2];
            for (int mt = 0; mt < 2; ++mt)
                af[mt] = *(const h8_t*)&UFF[(size_t)b * FB + (((kd * 8 + w * 2 + mt) * 64 + lane) << 3)];
            h8_t bf[8];
            for (int ot = 0; ot < 8; ++ot)
                bf[ot] = *(const h8_t*)&M0F[(size_t)(((kd * 24 + ob * 8 + ot) * 64 + lane) << 3)];
            for (int mt = 0; mt < 2; ++mt)
                for (int ot = 0; ot < 8; ++ot)
                    acc[mt][ot] = MFMA(af[mt], bf[ot], acc[mt][ot], 0, 0, 0);
        }
        for (int mt = 0; mt < 2; ++mt)
            for (int ot = 0; ot < 8; ++ot)
                for (int r = 0; r < 4; ++r) {
                    int nn = w * 32 + mt * 16 + q * 4 + r;
                    int o = ob * 128 + ot * 16 + l15;
                    V0T[((size_t)b * NC + nn) * DD + o] = (_Float16)acc[mt][ot][r];
                }
    }
}

// ---------------------------------------- Kchain2: VTB = V0 + G@(V0 + G@V0), per (b,ob)
// Column-block-local: both chain steps in one block; VTA lives in LDS (same f16
// rounding as the two-kernel version -> bit-identical).
__global__ __launch_bounds__(256) void k_chain2(
    const _Float16* __restrict__ V0T, const _Float16* __restrict__ GT,
    _Float16* __restrict__ VTB)
{
    __shared__ _Float16 T[128 * 136];
    const int b = blockIdx.x / 3, ob = blockIdx.x % 3;
    const int tid = threadIdx.x, lane = tid & 63, w = tid >> 6;
    const int q = lane >> 4, l15 = lane & 15;
    for (int p = 0; p < 8; ++p) {
        int j = p * 16 + (tid >> 4), o0 = (tid & 15) * 8;
        h8_t v = *(const h8_t*)&V0T[((size_t)b * NC + j) * DD + ob * 128 + o0];
        for (int i = 0; i < 8; ++i) T[(o0 + i) * 136 + j] = v[i];
    }
    __syncthreads();
    for (int step = 0; step < 2; ++step) {
        f32x4 acc[2][8];
        for (int mt = 0; mt < 2; ++mt)
            for (int ot = 0; ot < 8; ++ot) acc[mt][ot] = (f32x4){0.f, 0.f, 0.f, 0.f};
        for (int kd = 0; kd < 4; ++kd) {
            h8_t af[2];
            for (int mt = 0; mt < 2; ++mt) {
                int nn = w * 32 + mt * 16 + l15;
                af[mt] = *(const h8_t*)&GT[((size_t)b * NC + nn) * NC + kd * 32 + q * 8];
            }
            h8_t bf[8];
            for (int ot = 0; ot < 8; ++ot)
                bf[ot] = *(const h8_t*)&T[(ot * 16 + l15) * 136 + kd * 32 + q * 8];
            for (int mt = 0; mt < 2; ++mt)
                for (int ot = 0; ot < 8; ++ot)
                    acc[mt][ot] = MFMA(af[mt], bf[ot], acc[mt][ot], 0, 0, 0);
        }
        __syncthreads();  // all T reads done before overwrite / exit
        if (step == 0) {
            for (int mt = 0; mt < 2; ++mt)
                for (int ot = 0; ot < 8; ++ot)
                    for (int r = 0; r < 4; ++r) {
                        int nn = w * 32 + mt * 16 + q * 4 + r;
                        int ol = ot * 16 + l15;
                        size_t ix = ((size_t)b * NC + nn) * DD + ob * 128 + ol;
                        T[ol * 136 + nn] = (_Float16)((float)V0T[ix] + acc[mt][ot][r]);
                    }
            __syncthreads();
        } else {
            for (int mt = 0; mt < 2; ++mt)
                for (int ot = 0; ot < 8; ++ot)
                    for (int r = 0; r < 4; ++r) {
                        int nn = w * 32 + mt * 16 + q * 4 + r;
                        int ol = ot * 16 + l15;
                        size_t ix = ((size_t)b * NC + nn) * DD + ob * 128 + ol;
                        VTB[ix] = (_Float16)((float)V0T[ix] + acc[mt][ot][r]);
                    }
        }
    }
}

// ---------------------------- KwhatC: what (blocks 0..23) + transposes (24..71)
__global__ __launch_bounds__(256) void k_whatC(
    const _Float16* __restrict__ KFF, const _Float16* __restrict__ M0F,
    const _Float16* __restrict__ HT, const _Float16* __restrict__ VHT,
    const _Float16* __restrict__ KF, const float* __restrict__ TAB,
    float* __restrict__ SVP, float* __restrict__ SVVP,
    _Float16* __restrict__ WTH, _Float16* __restrict__ KFT,
    _Float16* __restrict__ WTF)
{
    __shared__ _Float16 T[128 * 136];
    const int tid = threadIdx.x, lane = tid & 63, w = tid >> 6;
    const int q = lane >> 4, l15 = lane & 15;
    if (blockIdx.x < 24) {  // ---- k_what ----
        const int b = blockIdx.x / 3, ob = blockIdx.x % 3;
        for (int p = 0; p < 8; ++p) {
            int j = p * 16 + (tid >> 4), o0 = (tid & 15) * 8;
            h8_t v = *(const h8_t*)&VHT[((size_t)b * NC + j) * DD + ob * 128 + o0];
            for (int i = 0; i < 8; ++i) T[(o0 + i) * 136 + j] = v[i];
        }
        __syncthreads();
        f32x4 acc[2][8];
        for (int mt = 0; mt < 2; ++mt)
            for (int ot = 0; ot < 8; ++ot) acc[mt][ot] = (f32x4){0.f, 0.f, 0.f, 0.f};
        for (int kd = 0; kd < 12; ++kd) {
            h8_t af[2];
            for (int mt = 0; mt < 2; ++mt)
                af[mt] = *(const h8_t*)&KFF[(size_t)b * FB + (((kd * 8 + w * 2 + mt) * 64 + lane) << 3)];
            h8_t bf[8];
            for (int ot = 0; ot < 8; ++ot)
                bf[ot] = *(const h8_t*)&M0F[(size_t)(((kd * 24 + ob * 8 + ot) * 64 + lane) << 3)];
            for (int mt = 0; mt < 2; ++mt)
                for (int ot = 0; ot < 8; ++ot)
                    acc[mt][ot] = MFMA(af[mt], bf[ot], acc[mt][ot], 0, 0, 0);
        }
        for (int kd = 0; kd < 4; ++kd) {
            h8_t af[2];
            for (int mt = 0; mt < 2; ++mt) {
                int nn = w * 32 + mt * 16 + l15;
                af[mt] = *(const h8_t*)&HT[((size_t)b * NC + nn) * NC + kd * 32 + q * 8];
            }
            h8_t bf[8];
            for (int ot = 0; ot < 8; ++ot)
                bf[ot] = *(const h8_t*)&T[(ot * 16 + l15) * 136 + kd * 32 + q * 8];
            for (int mt = 0; mt < 2; ++mt)
                for (int ot = 0; ot < 8; ++ot)
                    acc[mt][ot] = MFMA(af[mt], bf[ot], acc[mt][ot], 0, 0, 0);
        }
        for (int mt = 0; mt < 2; ++mt)
            for (int r = 0; r < 4; ++r) {
                int nn = w * 32 + mt * 16 + q * 4 + r;
                float sv = 0.f, svv = 0.f;
                for (int ot = 0; ot < 8; ++ot) {
                    float vh = (float)T[(ot * 16 + l15) * 136 + nn];
                    sv += acc[mt][ot][r] * vh;
                    svv += vh * vh;
                }
                sv += __shfl_xor(sv, 1); svv += __shfl_xor(svv, 1);
                sv += __shfl_xor(sv, 2); svv += __shfl_xor(svv, 2);
                sv += __shfl_xor(sv, 4); svv += __shfl_xor(svv, 4);
                sv += __shfl_xor(sv, 8); svv += __shfl_xor(svv, 8);
                if (l15 == 0) {
                    SVP[(b * 3 + ob) * NC + nn] = sv;
                    SVVP[(b * 3 + ob) * NC + nn] = svv;
                }
            }
    } else {  // ---- kC transposes ----
        const int idx = blockIdx.x - 24;
        const int b = idx / 6, ob = idx % 6;
        for (int pass = 0; pass < 2; ++pass) {
            const _Float16* Src = pass ? KF : VHT;
            _Float16* Dst = pass ? KFT : WTH;
            if (pass) __syncthreads();
            for (int pp = 0; pp < 4; ++pp) {
                int j = pp * 32 + (tid >> 3), oo = (tid & 7) * 8;
                *(h8_t*)&T[j * 72 + oo] =
                    *(const h8_t*)&Src[((size_t)b * NC + j) * DD + ob * 64 + oo];
            }
            __syncthreads();
            for (int c = 0; c < 4; ++c) {
                int idx2 = c * 256 + tid;
                int ol = idx2 >> 4, jc = (idx2 & 15) * 8;
                h8_t v;
                for (int i = 0; i < 8; ++i) {
                    float t = (float)T[(jc + i) * 72 + ol];
                    if (!pass) t *= TAB[b * NC + jc + i];
                    v[i] = (_Float16)t;
                }
                *(h8_t*)&Dst[((size_t)b * DD + ob * 64 + ol) * NC + jc] = v;
                if (!pass) {
                    int o = ob * 64 + ol, rt = o >> 4, l15o = o & 15;
                    int kb = jc >> 5, qq = (jc >> 3) & 3;
                    *(h8_t*)&WTF[(size_t)b * FB + (((kb * 24 + rt) * 64 + qq * 16 + l15o) << 3)] = v;
                }
            }
        }
    }
}

// ---------------------------------------------------------------- kscan
__global__ __launch_bounds__(256) void kscan(
    const float* __restrict__ M0, const float* __restrict__ AB,
    const float* __restrict__ SKK, const float* __restrict__ SVP,
    const float* __restrict__ SVVP,
    float* __restrict__ SIG, float* __restrict__ FRHO)
{
    __shared__ float sA[NC], sB[NC], sSV[NC], sVV[NC], sKK[NC], sig_s[NC];
    __shared__ float red[4];
    const int tid = threadIdx.x, b = blockIdx.x;
    for (int i = tid; i < NC; i += 256) {
        sA[i] = AB[(b * NC + i) * 2];
        sB[i] = AB[(b * NC + i) * 2 + 1];
        sSV[i] = SVP[(b * 3 + 0) * NC + i] + SVP[(b * 3 + 1) * NC + i]
                 + SVP[(b * 3 + 2) * NC + i];
        sVV[i] = SVVP[(b * 3 + 0) * NC + i] + SVVP[(b * 3 + 1) * NC + i]
                 + SVVP[(b * 3 + 2) * NC + i];
        sKK[i] = SKK[b * NC + i];
    }
    float p = 0.f;
    const float4* m4 = (const float4*)M0;
    for (int i = tid; i < DD * DD / 4; i += 256) {
        float4 v = m4[i];
        p += v.x * v.x + v.y * v.y + v.z * v.z + v.w * v.w;
    }
    for (int off = 32; off; off >>= 1) p += __shfl_xor(p, off);
    if ((tid & 63) == 0) red[tid >> 6] = p;
    __syncthreads();
    if (tid == 0) {
        float phi2 = red[0] + red[1] + red[2] + red[3];
        float an = 1.f, rho = 1.f;
        for (int n = 0; n < NC; ++n) {
            float A = sA[n], Bc = sB[n];
            sig_s[n] = rho * an;
            float a2 = an * an;
            phi2 = A * A * phi2 + 2.f * A * Bc * a2 * sSV[n]
                   + Bc * Bc * a2 * sVV[n] * sKK[n];
            float s = fminf(30.f / (rho * sqrtf(phi2) + 1e-6f), 1.f);
            rho *= s; an *= A;
        }
        FRHO[b] = rho * an;
    }
    __syncthreads();
    for (int i = tid; i < NC; i += 256) SIG[b * NC + i] = sig_s[i];
}

// ------------------------------------------------------------ K4: fused score+output
// 48 KB LDS (Ss aliases As): stage -> term1 -> QK^T(regs) -> bar -> Ss -> bar -> term2.
// 3 blocks/CU. Tail: M_fin.
__global__ __launch_bounds__(256, 3) void k4_out(
    const _Float16* __restrict__ XF, const _Float16* __restrict__ M0F,
    const _Float16* __restrict__ KFF, const _Float16* __restrict__ WTF,
    const _Float16* __restrict__ WTH, const _Float16* __restrict__ KFT,
    const float* __restrict__ SIG, const float* __restrict__ FRHO,
    const float* __restrict__ M0, float* __restrict__ out)
{
    const int tid = threadIdx.x, lane = tid & 63, w = tid >> 6;
    const int q = lane >> 4, l15 = lane & 15;

    if (blockIdx.x >= BB * NC) {  // M_fin tail: 96 WGs
        const int tw = blockIdx.x - BB * NC;
        const int b = tw / 12, sub = tw % 12;
        const int obk = sub >> 1, dh = sub & 1;
        const int o_t = obk * 64 + w * 16;
        f32x4 acc[12];
        for (int dt = 0; dt < 12; ++dt) acc[dt] = (f32x4){0.f, 0.f, 0.f, 0.f};
        for (int kd = 0; kd < 4; ++kd) {
            h8_t af = *(const h8_t*)&WTH[((size_t)b * DD + o_t + l15) * NC + kd * 32 + q * 8];
            for (int dt = 0; dt < 12; ++dt) {
                int d = dh * 192 + dt * 16 + l15;
                h8_t bf = *(const h8_t*)&KFT[((size_t)b * DD + d) * NC + kd * 32 + q * 8];
                acc[dt] = MFMA(af, bf, acc[dt], 0, 0, 0);
            }
        }
        float fr = FRHO[b];
        float* dst = out + (size_t)BB * SS * DD;
        for (int dt = 0; dt < 12; ++dt)
            for (int r = 0; r < 4; ++r) {
                int o = o_t + q * 4 + r, d = dh * 192 + dt * 16 + l15;
                dst[((size_t)b * DD + o) * DD + d] =
                    fr * (M0[(size_t)o * DD + d] + acc[dt][r]);
            }
        return;
    }

    __shared__ _Float16 As[CH * DD];   // 48 KB; Ss aliases first 16 KB
    _Float16* Ss = As;

    const int b = blockIdx.x >> 7, n = blockIdx.x & 127;
    const size_t chunk_off = (size_t)(b * SS + n * CH) * DD;
    const int nb = (n + 31) >> 5;

    // ---- stage chunk: contiguous 1KB bursts, swizzled LDS ----
    {
        const char* src = (const char*)(XF + chunk_off);
        char* dstb = (char*)As;
        for (int i = 0; i < 12; ++i) {
            int P = (w * 12 + i) * 1024 + lane * 16;
            int row = P / 768;
            int colS = P - row * 768;
            int colG = colS ^ ((row & 7) << 4);
            *(h8_t*)(dstb + P) = *(const h8_t*)(src + row * 768 + colG);
        }
    }
    __syncthreads();

    // ---- term1: chunk @ M0^T (reads As) ----
    f32x4 acc[4][6];
    for (int mi = 0; mi < 4; ++mi)
        for (int nj = 0; nj < 6; ++nj) acc[mi][nj] = (f32x4){0.f, 0.f, 0.f, 0.f};
    for (int kd = 0; kd < 12; ++kd) {
        h8_t af[4];
        for (int mi = 0; mi < 4; ++mi)
            af[mi] = LDSA(mi * 16 + l15, kd * 64 + q * 16);
        h8_t bf[6];
        for (int nj = 0; nj < 6; ++nj)
            bf[nj] = *(const h8_t*)&M0F[(size_t)(((kd * 24 + w * 6 + nj) * 64 + lane) << 3)];
        for (int mi = 0; mi < 4; ++mi)
            for (int nj = 0; nj < 6; ++nj)
                acc[mi][nj] = MFMA(af[mi], bf[nj], acc[mi][nj], 0, 0, 0);
    }

    // ---- phase A: S = chunk @ K^T into registers (reads As) ----
    f32x4 accS[4][2];
    if (w * 32 < n) {
        for (int mi = 0; mi < 4; ++mi)
            for (int nj = 0; nj < 2; ++nj) accS[mi][nj] = (f32x4){0.f, 0.f, 0.f, 0.f};
        for (int kd = 0; kd < 12; ++kd) {
            h8_t af[4];
            for (int mi = 0; mi < 4; ++mi)
                af[mi] = LDSA(mi * 16 + l15, kd * 64 + q * 16);
            h8_t bfk[2];
            for (int nj = 0; nj < 2; ++nj)
                bfk[nj] = *(const h8_t*)&KFF[(size_t)b * FB + (((kd * 8 + w * 2 + nj) * 64 + lane) << 3)];
            for (int mi = 0; mi < 4; ++mi)
                for (int nj = 0; nj < 2; ++nj)
                    accS[mi][nj] = MFMA(af[mi], bfk[nj], accS[mi][nj], 0, 0, 0);
        }
    }
    __syncthreads();   // all As reads done before Ss overwrite

    if (w * 32 < n) {
        for (int mi = 0; mi < 4; ++mi)
            for (int nj = 0; nj < 2; ++nj)
                for (int r = 0; r < 4; ++r) {
                    int c = mi * 16 + q * 4 + r, j = w * 32 + nj * 16 + l15;
                    _Float16 sv = (_Float16)((j < n) ? accS[mi][nj][r] : 0.f);
                    *(_Float16*)((char*)Ss + c * 256 + ((j * 2) ^ ((c & 7) << 4))) = sv;
                }
    }
    __syncthreads();

    // ---- term2: + S @ WTH^T ----
    for (int kb = 0; kb < nb; ++kb) {
        h8_t af[4];
        for (int mi = 0; mi < 4; ++mi)
            af[mi] = LDSS(mi * 16 + l15, kb * 64 + q * 16);
        h8_t bf[6];
        for (int nj = 0; nj < 6; ++nj)
            bf[nj] = *(const h8_t*)&WTF[(size_t)b * FB + (((kb * 24 + w * 6 + nj) * 64 + lane) << 3)];
        for (int mi = 0; mi < 4; ++mi)
            for (int nj = 0; nj < 6; ++nj)
                acc[mi][nj] = MFMA(af[mi], bf[nj], acc[mi][nj], 0, 0, 0);
    }

    const float sg = SIG[b * NC + n];
    for (int mi = 0; mi < 4; ++mi)
        for (int nj = 0; nj < 6; ++nj)
            for (int r = 0; r < 4; ++r) {
                int c = mi * 16 + q * 4 + r, o = w * 96 + nj * 16 + l15;
                out[chunk_off + (size_t)c * DD + o] = sg * acc[mi][nj][r];
            }
}

// ---------------------------------------------------------------- launch
extern "C" void kernel_launch(void* const* d_in, const int* in_sizes, int n_in,
                              void* d_out, int out_size, void* d_ws, size_t ws_size,
                              hipStream_t stream) {
    (void)in_sizes; (void)n_in; (void)out_size; (void)ws_size;
    const float* x         = (const float*)d_in[0];
    const float* M0        = (const float*)d_in[1];
    const float* eta_raw   = (const float*)d_in[2];
    const float* alpha_raw = (const float*)d_in[3];
    const float* gate_w    = (const float*)d_in[4];
    const float* gate_b    = (const float*)d_in[5];
    float* out = (float*)d_out;
    char* ws = (char*)d_ws;

    _Float16* XF  = (_Float16*)(ws);                 // 50,331,648
    _Float16* KF  = (_Float16*)(ws + 51118080);      //    786,432
    _Float16* GT  = (_Float16*)(ws + 52199424);      //    262,144
    _Float16* HT  = (_Float16*)(ws + 52461568);      //    262,144
    _Float16* V0T = (_Float16*)(ws + 52723712);      //    786,432
    _Float16* VTB = (_Float16*)(ws + 54296576);      //    786,432
    _Float16* WTH = (_Float16*)(ws + 55083008);      //    786,432
    _Float16* KFT = (_Float16*)(ws + 55869440);      //    786,432
    _Float16* M0F = (_Float16*)(ws + 56655872);      //    294,912
    _Float16* KFF = (_Float16*)(ws + 56950784);      //    786,432
    _Float16* UFF = (_Float16*)(ws + 57737216);      //    786,432
    _Float16* WTF = (_Float16*)(ws + 58523648);      //    786,432
    float*    AB  = (float*)(ws + 73433088);         //      8,192
    float*    TAB = (float*)(ws + 73441280);         //      4,096
    float*    SKK = (float*)(ws + 73445376);         //      4,096
    float*    SVP = (float*)(ws + 73449472);         //     12,288
    float*    SVVP= (float*)(ws + 73461760);         //     12,288
    float*    SIG = (float*)(ws + 73474048);         //      4,096
    float*    FRHO= (float*)(ws + 73478144);         //        256

    k1_stats<<<dim3(BB * NC), dim3(512), 0, stream>>>(
        x, M0, eta_raw, alpha_raw, gate_w, gate_b, XF, KF, KFF, UFF,
        AB, TAB, SKK, M0F);
    kA<<<dim3(8 + BB * 3), dim3(256), 0, stream>>>(KFF, UFF, M0F, TAB, GT, HT, V0T);
    k_chain2<<<dim3(BB * 3), dim3(256), 0, stream>>>(V0T, GT, VTB);
    k_whatC<<<dim3(24 + 48), dim3(256), 0, stream>>>(
        KFF, M0F, HT, VTB, KF, TAB, SVP, SVVP, WTH, KFT, WTF);
    kscan<<<dim3(BB), dim3(256), 0, stream>>>(M0, AB, SKK, SVP, SVVP, SIG, FRHO);
    k4_out<<<dim3(BB * NC + 96), dim3(256), 0, stream>>>(
        XF, M0F, KFF, WTF, WTH, KFT, SIG, FRHO, M0, out);
}

// Round 7
// 368.755 us; speedup vs baseline: 1.1707x; 1.1707x over previous
//
#include <hip/hip_runtime.h>
#include <cmath>

#define BB 8
#define SS 8192
#define DD 384
#define CH 64
#define NC 128
#define FB 49152   // fragment-linear block per batch

typedef _Float16 h8_t __attribute__((ext_vector_type(8)));
typedef _Float16 h4_t __attribute__((ext_vector_type(4)));
typedef float f32x4 __attribute__((ext_vector_type(4)));

#define MFMA __builtin_amdgcn_mfma_f32_16x16x32_f16

// swizzled LDS accessors
#define LDSA(row, colb) (*(const h8_t*)((const char*)As + (size_t)(row) * 768 + (((colb)) ^ ((((row)) & 7) << 4))))
#define LDSS(row, colb) (*(const h8_t*)((const char*)Ss + (size_t)(row) * 256 + (((colb)) ^ ((((row)) & 7) << 4))))

// ---------------------------------------------------------------- K1: stats
__global__ __launch_bounds__(512) void k1_stats(
    const float* __restrict__ x, const float* __restrict__ M0,
    const float* __restrict__ eta_raw, const float* __restrict__ alpha_raw,
    const float* __restrict__ gate_w, const float* __restrict__ gate_b,
    _Float16* __restrict__ XF, _Float16* __restrict__ KF,
    _Float16* __restrict__ KFF, _Float16* __restrict__ UFF,
    float* __restrict__ AB, float* __restrict__ TAB,
    float* __restrict__ SKK, _Float16* __restrict__ M0F)
{
    __shared__ _Float16 ch[CH * 392];   // 50176 B
    __shared__ float rinv[CH];
    __shared__ float kmS[DD], uS[DD];
    __shared__ float redg[8], redk[8];
    const int wg = blockIdx.x, tid = threadIdx.x;
    const int b = wg >> 7, n = wg & 127;
    const int lane = tid & 63, wid = tid >> 6;

    if (wg < 64 && tid < 288) {  // M0 -> f16 fragment-linear
        int rl = tid / 48, c = tid % 48, kd = c >> 2, q = c & 3;
        int o = wg * 6 + rl, rt = o >> 4, l15o = o & 15;
        h8_t v;
        for (int i = 0; i < 8; ++i)
            v[i] = (_Float16)M0[(size_t)o * DD + kd * 32 + q * 8 + i];
        *(h8_t*)&M0F[(size_t)(((kd * 24 + rt) * 64 + q * 16 + l15o) << 3)] = v;
    }

    const size_t chunk_off = (size_t)(b * SS + n * CH) * DD;
    const float4* __restrict__ xin = (const float4*)(x + chunk_off);
    h4_t* __restrict__ xf = (h4_t*)(XF + chunk_off);
    for (int i = tid; i < CH * DD / 4; i += 512) {
        float4 v = xin[i];
        int base = i * 4, r = base / DD, c = base % DD;
        h4_t h; h[0] = (_Float16)v.x; h[1] = (_Float16)v.y;
        h[2] = (_Float16)v.z; h[3] = (_Float16)v.w;
        *(h4_t*)&ch[r * 392 + c] = h;
        xf[i] = h;
    }
    __syncthreads();

    for (int r = wid * 8; r < wid * 8 + 8; ++r) {
        float s = 0.f;
        for (int t = 0; t < 6; ++t) {
            float v = (float)ch[r * 392 + lane + 64 * t]; s += v * v;
        }
        for (int off = 32; off; off >>= 1) s += __shfl_xor(s, off);
        if (lane == 0) rinv[r] = 1.f / fmaxf(sqrtf(s), 1e-5f);
    }
    __syncthreads();

    float gpart = 0.f, skkp = 0.f;
    for (int d = tid; d < DD; d += 512) {
        float xa = 0.f, km = 0.f;
        for (int c = 0; c < CH; ++c) {
            float v = (float)ch[c * 392 + d]; xa += v; km += v * rinv[c];
        }
        xa *= (1.f / 64.f); km *= (1.f / 64.f);
        KF[(size_t)(b * NC + n) * DD + d] = (_Float16)km;
        kmS[d] = km; uS[d] = xa - km;
        gpart += km * gate_w[d];
        skkp += km * km;
    }
    for (int off = 32; off; off >>= 1) {
        gpart += __shfl_xor(gpart, off);
        skkp += __shfl_xor(skkp, off);
    }
    if (lane == 0) { redg[wid] = gpart; redk[wid] = skkp; }
    __syncthreads();
    if (tid == 0) {
        float gsum = 0.f, ks = 0.f;
        for (int i = 0; i < 8; ++i) { gsum += redg[i]; ks += redk[i]; }
        float g = 1.f / (1.f + expf(-(gsum + gate_b[0])));
        float eta = 0.2f / (1.f + expf(-eta_raw[0]));
        float alpha = 0.5f + 0.5f / (1.f + expf(-alpha_raw[0]));
        float A = g * alpha + 1.f - g;
        float Bc = g * eta;
        AB[wg * 2 + 0] = A;
        AB[wg * 2 + 1] = Bc;
        TAB[wg] = Bc / A;
        SKK[wg] = ks;
    }
    if (tid < 96) {  // KFF / UFF fragment-linear slivers for row n
        int isU = tid >= 48, c = tid & 47;
        int kd = c >> 2, q = c & 3;
        int rt = n >> 4, l15n = n & 15;
        h8_t v;
        for (int i = 0; i < 8; ++i)
            v[i] = (_Float16)(isU ? uS[kd * 32 + q * 8 + i] : kmS[kd * 32 + q * 8 + i]);
        _Float16* dst = isU ? UFF : KFF;
        *(h8_t*)&dst[(size_t)b * FB + (((kd * 8 + rt) * 64 + q * 16 + l15n) << 3)] = v;
    }
}

// ---------------------------------------------------------------- kA: gram + v0
__global__ __launch_bounds__(256) void kA(
    const _Float16* __restrict__ KFF, const _Float16* __restrict__ UFF,
    const _Float16* __restrict__ M0F, const float* __restrict__ TAB,
    _Float16* __restrict__ GT, _Float16* __restrict__ HT,
    _Float16* __restrict__ V0T)
{
    const int tid = threadIdx.x, lane = tid & 63, w = tid >> 6;
    const int q = lane >> 4, l15 = lane & 15;
    if (blockIdx.x < 8) {
        const int b = blockIdx.x;
        for (int pass = 0; pass < 2; ++pass) {
            const _Float16* Bm = pass ? KFF : UFF;
            _Float16* Out = pass ? HT : GT;
            f32x4 acc[2][8];
            for (int mt = 0; mt < 2; ++mt)
                for (int nt = 0; nt < 8; ++nt) acc[mt][nt] = (f32x4){0.f, 0.f, 0.f, 0.f};
            for (int kd = 0; kd < 12; ++kd) {
                h8_t af[2];
                for (int mt = 0; mt < 2; ++mt)
                    af[mt] = *(const h8_t*)&KFF[(size_t)b * FB + (((kd * 8 + w * 2 + mt) * 64 + lane) << 3)];
                h8_t bf[8];
                for (int nt = 0; nt < 8; ++nt)
                    bf[nt] = *(const h8_t*)&Bm[(size_t)b * FB + (((kd * 8 + nt) * 64 + lane) << 3)];
                for (int mt = 0; mt < 2; ++mt)
                    for (int nt = 0; nt < 8; ++nt)
                        acc[mt][nt] = MFMA(af[mt], bf[nt], acc[mt][nt], 0, 0, 0);
            }
            for (int mt = 0; mt < 2; ++mt)
                for (int nt = 0; nt < 8; ++nt)
                    for (int r = 0; r < 4; ++r) {
                        int j = w * 32 + mt * 16 + q * 4 + r;
                        int nn = nt * 16 + l15;
                        float v = (j < nn) ? TAB[b * NC + j] * acc[mt][nt][r] : 0.f;
                        Out[((size_t)b * NC + nn) * NC + j] = (_Float16)v;
                    }
        }
    } else {
        const int idx = blockIdx.x - 8;
        const int b = idx / 3, ob = idx % 3;
        f32x4 acc[2][8];
        for (int mt = 0; mt < 2; ++mt)
            for (int ot = 0; ot < 8; ++ot) acc[mt][ot] = (f32x4){0.f, 0.f, 0.f, 0.f};
        for (int kd = 0; kd < 12; ++kd) {
            h8_t af[2];
            for (int mt = 0; mt < 2; ++mt)
                af[mt] = *(const h8_t*)&UFF[(size_t)b * FB + (((kd * 8 + w * 2 + mt) * 64 + lane) << 3)];
            h8_t bf[8];
            for (int ot = 0; ot < 8; ++ot)
                bf[ot] = *(const h8_t*)&M0F[(size_t)(((kd * 24 + ob * 8 + ot) * 64 + lane) << 3)];
            for (int mt = 0; mt < 2; ++mt)
                for (int ot = 0; ot < 8; ++ot)
                    acc[mt][ot] = MFMA(af[mt], bf[ot], acc[mt][ot], 0, 0, 0);
        }
        for (int mt = 0; mt < 2; ++mt)
            for (int ot = 0; ot < 8; ++ot)
                for (int r = 0; r < 4; ++r) {
                    int nn = w * 32 + mt * 16 + q * 4 + r;
                    int o = ob * 128 + ot * 16 + l15;
                    V0T[((size_t)b * NC + nn) * DD + o] = (_Float16)acc[mt][ot][r];
                }
    }
}

// ---------------------------------------- Kchain2: VTB = V0 + G@(V0 + G@V0), per (b,ob)
__global__ __launch_bounds__(256) void k_chain2(
    const _Float16* __restrict__ V0T, const _Float16* __restrict__ GT,
    _Float16* __restrict__ VTB)
{
    __shared__ _Float16 T[128 * 136];
    const int b = blockIdx.x / 3, ob = blockIdx.x % 3;
    const int tid = threadIdx.x, lane = tid & 63, w = tid >> 6;
    const int q = lane >> 4, l15 = lane & 15;
    for (int p = 0; p < 8; ++p) {
        int j = p * 16 + (tid >> 4), o0 = (tid & 15) * 8;
        h8_t v = *(const h8_t*)&V0T[((size_t)b * NC + j) * DD + ob * 128 + o0];
        for (int i = 0; i < 8; ++i) T[(o0 + i) * 136 + j] = v[i];
    }
    __syncthreads();
    for (int step = 0; step < 2; ++step) {
        f32x4 acc[2][8];
        for (int mt = 0; mt < 2; ++mt)
            for (int ot = 0; ot < 8; ++ot) acc[mt][ot] = (f32x4){0.f, 0.f, 0.f, 0.f};
        for (int kd = 0; kd < 4; ++kd) {
            h8_t af[2];
            for (int mt = 0; mt < 2; ++mt) {
                int nn = w * 32 + mt * 16 + l15;
                af[mt] = *(const h8_t*)&GT[((size_t)b * NC + nn) * NC + kd * 32 + q * 8];
            }
            h8_t bf[8];
            for (int ot = 0; ot < 8; ++ot)
                bf[ot] = *(const h8_t*)&T[(ot * 16 + l15) * 136 + kd * 32 + q * 8];
            for (int mt = 0; mt < 2; ++mt)
                for (int ot = 0; ot < 8; ++ot)
                    acc[mt][ot] = MFMA(af[mt], bf[ot], acc[mt][ot], 0, 0, 0);
        }
        __syncthreads();  // all T reads done before overwrite / exit
        if (step == 0) {
            for (int mt = 0; mt < 2; ++mt)
                for (int ot = 0; ot < 8; ++ot)
                    for (int r = 0; r < 4; ++r) {
                        int nn = w * 32 + mt * 16 + q * 4 + r;
                        int ol = ot * 16 + l15;
                        size_t ix = ((size_t)b * NC + nn) * DD + ob * 128 + ol;
                        T[ol * 136 + nn] = (_Float16)((float)V0T[ix] + acc[mt][ot][r]);
                    }
            __syncthreads();
        } else {
            for (int mt = 0; mt < 2; ++mt)
                for (int ot = 0; ot < 8; ++ot)
                    for (int r = 0; r < 4; ++r) {
                        int nn = w * 32 + mt * 16 + q * 4 + r;
                        int ol = ot * 16 + l15;
                        size_t ix = ((size_t)b * NC + nn) * DD + ob * 128 + ol;
                        VTB[ix] = (_Float16)((float)V0T[ix] + acc[mt][ot][r]);
                    }
        }
    }
}

// ---------------------------- KwhatC: what (blocks 0..23) + transposes (24..71)
__global__ __launch_bounds__(256) void k_whatC(
    const _Float16* __restrict__ KFF, const _Float16* __restrict__ M0F,
    const _Float16* __restrict__ HT, const _Float16* __restrict__ VHT,
    const _Float16* __restrict__ KF, const float* __restrict__ TAB,
    float* __restrict__ SVP, float* __restrict__ SVVP,
    _Float16* __restrict__ WTH, _Float16* __restrict__ KFT,
    _Float16* __restrict__ WTF)
{
    __shared__ _Float16 T[128 * 136];
    const int tid = threadIdx.x, lane = tid & 63, w = tid >> 6;
    const int q = lane >> 4, l15 = lane & 15;
    if (blockIdx.x < 24) {  // ---- k_what ----
        const int b = blockIdx.x / 3, ob = blockIdx.x % 3;
        for (int p = 0; p < 8; ++p) {
            int j = p * 16 + (tid >> 4), o0 = (tid & 15) * 8;
            h8_t v = *(const h8_t*)&VHT[((size_t)b * NC + j) * DD + ob * 128 + o0];
            for (int i = 0; i < 8; ++i) T[(o0 + i) * 136 + j] = v[i];
        }
        __syncthreads();
        f32x4 acc[2][8];
        for (int mt = 0; mt < 2; ++mt)
            for (int ot = 0; ot < 8; ++ot) acc[mt][ot] = (f32x4){0.f, 0.f, 0.f, 0.f};
        for (int kd = 0; kd < 12; ++kd) {
            h8_t af[2];
            for (int mt = 0; mt < 2; ++mt)
                af[mt] = *(const h8_t*)&KFF[(size_t)b * FB + (((kd * 8 + w * 2 + mt) * 64 + lane) << 3)];
            h8_t bf[8];
            for (int ot = 0; ot < 8; ++ot)
                bf[ot] = *(const h8_t*)&M0F[(size_t)(((kd * 24 + ob * 8 + ot) * 64 + lane) << 3)];
            for (int mt = 0; mt < 2; ++mt)
                for (int ot = 0; ot < 8; ++ot)
                    acc[mt][ot] = MFMA(af[mt], bf[ot], acc[mt][ot], 0, 0, 0);
        }
        for (int kd = 0; kd < 4; ++kd) {
            h8_t af[2];
            for (int mt = 0; mt < 2; ++mt) {
                int nn = w * 32 + mt * 16 + l15;
                af[mt] = *(const h8_t*)&HT[((size_t)b * NC + nn) * NC + kd * 32 + q * 8];
            }
            h8_t bf[8];
            for (int ot = 0; ot < 8; ++ot)
                bf[ot] = *(const h8_t*)&T[(ot * 16 + l15) * 136 + kd * 32 + q * 8];
            for (int mt = 0; mt < 2; ++mt)
                for (int ot = 0; ot < 8; ++ot)
                    acc[mt][ot] = MFMA(af[mt], bf[ot], acc[mt][ot], 0, 0, 0);
        }
        for (int mt = 0; mt < 2; ++mt)
            for (int r = 0; r < 4; ++r) {
                int nn = w * 32 + mt * 16 + q * 4 + r;
                float sv = 0.f, svv = 0.f;
                for (int ot = 0; ot < 8; ++ot) {
                    float vh = (float)T[(ot * 16 + l15) * 136 + nn];
                    sv += acc[mt][ot][r] * vh;
                    svv += vh * vh;
                }
                sv += __shfl_xor(sv, 1); svv += __shfl_xor(svv, 1);
                sv += __shfl_xor(sv, 2); svv += __shfl_xor(svv, 2);
                sv += __shfl_xor(sv, 4); svv += __shfl_xor(svv, 4);
                sv += __shfl_xor(sv, 8); svv += __shfl_xor(svv, 8);
                if (l15 == 0) {
                    SVP[(b * 3 + ob) * NC + nn] = sv;
                    SVVP[(b * 3 + ob) * NC + nn] = svv;
                }
            }
    } else {  // ---- kC transposes ----
        const int idx = blockIdx.x - 24;
        const int b = idx / 6, ob = idx % 6;
        for (int pass = 0; pass < 2; ++pass) {
            const _Float16* Src = pass ? KF : VHT;
            _Float16* Dst = pass ? KFT : WTH;
            if (pass) __syncthreads();
            for (int pp = 0; pp < 4; ++pp) {
                int j = pp * 32 + (tid >> 3), oo = (tid & 7) * 8;
                *(h8_t*)&T[j * 72 + oo] =
                    *(const h8_t*)&Src[((size_t)b * NC + j) * DD + ob * 64 + oo];
            }
            __syncthreads();
            for (int c = 0; c < 4; ++c) {
                int idx2 = c * 256 + tid;
                int ol = idx2 >> 4, jc = (idx2 & 15) * 8;
                h8_t v;
                for (int i = 0; i < 8; ++i) {
                    float t = (float)T[(jc + i) * 72 + ol];
                    if (!pass) t *= TAB[b * NC + jc + i];
                    v[i] = (_Float16)t;
                }
                *(h8_t*)&Dst[((size_t)b * DD + ob * 64 + ol) * NC + jc] = v;
                if (!pass) {
                    int o = ob * 64 + ol, rt = o >> 4, l15o = o & 15;
                    int kb = jc >> 5, qq = (jc >> 3) & 3;
                    *(h8_t*)&WTF[(size_t)b * FB + (((kb * 24 + rt) * 64 + qq * 16 + l15o) << 3)] = v;
                }
            }
        }
    }
}

// ---------------------------------------------------------------- kscan
__global__ __launch_bounds__(256) void kscan(
    const float* __restrict__ M0, const float* __restrict__ AB,
    const float* __restrict__ SKK, const float* __restrict__ SVP,
    const float* __restrict__ SVVP,
    float* __restrict__ SIG, float* __restrict__ FRHO)
{
    __shared__ float sA[NC], sB[NC], sSV[NC], sVV[NC], sKK[NC], sig_s[NC];
    __shared__ float red[4];
    const int tid = threadIdx.x, b = blockIdx.x;
    for (int i = tid; i < NC; i += 256) {
        sA[i] = AB[(b * NC + i) * 2];
        sB[i] = AB[(b * NC + i) * 2 + 1];
        sSV[i] = SVP[(b * 3 + 0) * NC + i] + SVP[(b * 3 + 1) * NC + i]
                 + SVP[(b * 3 + 2) * NC + i];
        sVV[i] = SVVP[(b * 3 + 0) * NC + i] + SVVP[(b * 3 + 1) * NC + i]
                 + SVVP[(b * 3 + 2) * NC + i];
        sKK[i] = SKK[b * NC + i];
    }
    float p = 0.f;
    const float4* m4 = (const float4*)M0;
    for (int i = tid; i < DD * DD / 4; i += 256) {
        float4 v = m4[i];
        p += v.x * v.x + v.y * v.y + v.z * v.z + v.w * v.w;
    }
    for (int off = 32; off; off >>= 1) p += __shfl_xor(p, off);
    if ((tid & 63) == 0) red[tid >> 6] = p;
    __syncthreads();
    if (tid == 0) {
        float phi2 = red[0] + red[1] + red[2] + red[3];
        float an = 1.f, rho = 1.f;
        for (int n = 0; n < NC; ++n) {
            float A = sA[n], Bc = sB[n];
            sig_s[n] = rho * an;
            float a2 = an * an;
            phi2 = A * A * phi2 + 2.f * A * Bc * a2 * sSV[n]
                   + Bc * Bc * a2 * sVV[n] * sKK[n];
            float s = fminf(30.f / (rho * sqrtf(phi2) + 1e-6f), 1.f);
            rho *= s; an *= A;
        }
        FRHO[b] = rho * an;
    }
    __syncthreads();
    for (int i = tid; i < NC; i += 256) SIG[b * NC + i] = sig_s[i];
}

// ------------------------------------------------------------ K4: fused score+output
// 64 KB LDS (As + separate Ss), launch_bounds(256,2): accS dies before acc is
// born -> no spill (round-6 lesson: (256,3)+aliasing spilled 250 MB to scratch).
__global__ __launch_bounds__(256, 2) void k4_out(
    const _Float16* __restrict__ XF, const _Float16* __restrict__ M0F,
    const _Float16* __restrict__ KFF, const _Float16* __restrict__ WTF,
    const _Float16* __restrict__ WTH, const _Float16* __restrict__ KFT,
    const float* __restrict__ SIG, const float* __restrict__ FRHO,
    const float* __restrict__ M0, float* __restrict__ out)
{
    const int tid = threadIdx.x, lane = tid & 63, w = tid >> 6;
    const int q = lane >> 4, l15 = lane & 15;

    if (blockIdx.x >= BB * NC) {  // M_fin tail: 96 WGs
        const int tw = blockIdx.x - BB * NC;
        const int b = tw / 12, sub = tw % 12;
        const int obk = sub >> 1, dh = sub & 1;
        const int o_t = obk * 64 + w * 16;
        f32x4 acc[12];
        for (int dt = 0; dt < 12; ++dt) acc[dt] = (f32x4){0.f, 0.f, 0.f, 0.f};
        for (int kd = 0; kd < 4; ++kd) {
            h8_t af = *(const h8_t*)&WTH[((size_t)b * DD + o_t + l15) * NC + kd * 32 + q * 8];
            for (int dt = 0; dt < 12; ++dt) {
                int d = dh * 192 + dt * 16 + l15;
                h8_t bf = *(const h8_t*)&KFT[((size_t)b * DD + d) * NC + kd * 32 + q * 8];
                acc[dt] = MFMA(af, bf, acc[dt], 0, 0, 0);
            }
        }
        float fr = FRHO[b];
        float* dst = out + (size_t)BB * SS * DD;
        for (int dt = 0; dt < 12; ++dt)
            for (int r = 0; r < 4; ++r) {
                int o = o_t + q * 4 + r, d = dh * 192 + dt * 16 + l15;
                dst[((size_t)b * DD + o) * DD + d] =
                    fr * (M0[(size_t)o * DD + d] + acc[dt][r]);
            }
        return;
    }

    __shared__ _Float16 As[CH * DD];   // 48 KB
    __shared__ _Float16 Ss[CH * NC];   // 16 KB (separate; no aliasing)

    const int b = blockIdx.x >> 7, n = blockIdx.x & 127;
    const size_t chunk_off = (size_t)(b * SS + n * CH) * DD;
    const int nb = (n + 31) >> 5;

    // ---- stage chunk: contiguous 1KB bursts, swizzled LDS ----
    {
        const char* src = (const char*)(XF + chunk_off);
        char* dstb = (char*)As;
        for (int i = 0; i < 12; ++i) {
            int P = (w * 12 + i) * 1024 + lane * 16;
            int row = P / 768;
            int colS = P - row * 768;
            int colG = colS ^ ((row & 7) << 4);
            *(h8_t*)(dstb + P) = *(const h8_t*)(src + row * 768 + colG);
        }
    }
    __syncthreads();

    // ---- phase A: S-tile = chunk @ K^T -> LDS (accS dies here) ----
    if (w * 32 < n) {
        f32x4 accS[4][2];
        for (int mi = 0; mi < 4; ++mi)
            for (int nj = 0; nj < 2; ++nj) accS[mi][nj] = (f32x4){0.f, 0.f, 0.f, 0.f};
        for (int kd = 0; kd < 12; ++kd) {
            h8_t af[4];
            for (int mi = 0; mi < 4; ++mi)
                af[mi] = LDSA(mi * 16 + l15, kd * 64 + q * 16);
            h8_t bfk[2];
            for (int nj = 0; nj < 2; ++nj)
                bfk[nj] = *(const h8_t*)&KFF[(size_t)b * FB + (((kd * 8 + w * 2 + nj) * 64 + lane) << 3)];
            for (int mi = 0; mi < 4; ++mi)
                for (int nj = 0; nj < 2; ++nj)
                    accS[mi][nj] = MFMA(af[mi], bfk[nj], accS[mi][nj], 0, 0, 0);
        }
        for (int mi = 0; mi < 4; ++mi)
            for (int nj = 0; nj < 2; ++nj)
                for (int r = 0; r < 4; ++r) {
                    int c = mi * 16 + q * 4 + r, j = w * 32 + nj * 16 + l15;
                    _Float16 sv = (_Float16)((j < n) ? accS[mi][nj][r] : 0.f);
                    *(_Float16*)((char*)Ss + c * 256 + ((j * 2) ^ ((c & 7) << 4))) = sv;
                }
    }
    __syncthreads();

    // ---- phase C: out = chunk @ M0^T + S @ WTH^T ----
    f32x4 acc[4][6];
    for (int mi = 0; mi < 4; ++mi)
        for (int nj = 0; nj < 6; ++nj) acc[mi][nj] = (f32x4){0.f, 0.f, 0.f, 0.f};

    for (int kd = 0; kd < 12; ++kd) {  // term1: chunk @ M0^T
        h8_t af[4];
        for (int mi = 0; mi < 4; ++mi)
            af[mi] = LDSA(mi * 16 + l15, kd * 64 + q * 16);
        h8_t bf[6];
        for (int nj = 0; nj < 6; ++nj)
            bf[nj] = *(const h8_t*)&M0F[(size_t)(((kd * 24 + w * 6 + nj) * 64 + lane) << 3)];
        for (int mi = 0; mi < 4; ++mi)
            for (int nj = 0; nj < 6; ++nj)
                acc[mi][nj] = MFMA(af[mi], bf[nj], acc[mi][nj], 0, 0, 0);
    }

    for (int kb = 0; kb < nb; ++kb) {  // + S @ WTH^T
        h8_t af[4];
        for (int mi = 0; mi < 4; ++mi)
            af[mi] = LDSS(mi * 16 + l15, kb * 64 + q * 16);
        h8_t bf[6];
        for (int nj = 0; nj < 6; ++nj)
            bf[nj] = *(const h8_t*)&WTF[(size_t)b * FB + (((kb * 24 + w * 6 + nj) * 64 + lane) << 3)];
        for (int mi = 0; mi < 4; ++mi)
            for (int nj = 0; nj < 6; ++nj)
                acc[mi][nj] = MFMA(af[mi], bf[nj], acc[mi][nj], 0, 0, 0);
    }

    const float sg = SIG[b * NC + n];
    for (int mi = 0; mi < 4; ++mi)
        for (int nj = 0; nj < 6; ++nj)
            for (int r = 0; r < 4; ++r) {
                int c = mi * 16 + q * 4 + r, o = w * 96 + nj * 16 + l15;
                out[chunk_off + (size_t)c * DD + o] = sg * acc[mi][nj][r];
            }
}

// ---------------------------------------------------------------- launch
extern "C" void kernel_launch(void* const* d_in, const int* in_sizes, int n_in,
                              void* d_out, int out_size, void* d_ws, size_t ws_size,
                              hipStream_t stream) {
    (void)in_sizes; (void)n_in; (void)out_size; (void)ws_size;
    const float* x         = (const float*)d_in[0];
    const float* M0        = (const float*)d_in[1];
    const float* eta_raw   = (const float*)d_in[2];
    const float* alpha_raw = (const float*)d_in[3];
    const float* gate_w    = (const float*)d_in[4];
    const float* gate_b    = (const float*)d_in[5];
    float* out = (float*)d_out;
    char* ws = (char*)d_ws;

    _Float16* XF  = (_Float16*)(ws);                 // 50,331,648
    _Float16* KF  = (_Float16*)(ws + 51118080);      //    786,432
    _Float16* GT  = (_Float16*)(ws + 52199424);      //    262,144
    _Float16* HT  = (_Float16*)(ws + 52461568);      //    262,144
    _Float16* V0T = (_Float16*)(ws + 52723712);      //    786,432
    _Float16* VTB = (_Float16*)(ws + 54296576);      //    786,432
    _Float16* WTH = (_Float16*)(ws + 55083008);      //    786,432
    _Float16* KFT = (_Float16*)(ws + 55869440);      //    786,432
    _Float16* M0F = (_Float16*)(ws + 56655872);      //    294,912
    _Float16* KFF = (_Float16*)(ws + 56950784);      //    786,432
    _Float16* UFF = (_Float16*)(ws + 57737216);      //    786,432
    _Float16* WTF = (_Float16*)(ws + 58523648);      //    786,432
    float*    AB  = (float*)(ws + 73433088);         //      8,192
    float*    TAB = (float*)(ws + 73441280);         //      4,096
    float*    SKK = (float*)(ws + 73445376);         //      4,096
    float*    SVP = (float*)(ws + 73449472);         //     12,288
    float*    SVVP= (float*)(ws + 73461760);         //     12,288
    float*    SIG = (float*)(ws + 73474048);         //      4,096
    float*    FRHO= (float*)(ws + 73478144);         //        256

    k1_stats<<<dim3(BB * NC), dim3(512), 0, stream>>>(
        x, M0, eta_raw, alpha_raw, gate_w, gate_b, XF, KF, KFF, UFF,
        AB, TAB, SKK, M0F);
    kA<<<dim3(8 + BB * 3), dim3(256), 0, stream>>>(KFF, UFF, M0F, TAB, GT, HT, V0T);
    k_chain2<<<dim3(BB * 3), dim3(256), 0, stream>>>(V0T, GT, VTB);
    k_whatC<<<dim3(24 + 48), dim3(256), 0, stream>>>(
        KFF, M0F, HT, VTB, KF, TAB, SVP, SVVP, WTH, KFT, WTF);
    kscan<<<dim3(BB), dim3(256), 0, stream>>>(M0, AB, SKK, SVP, SVVP, SIG, FRHO);
    k4_out<<<dim3(BB * NC + 96), dim3(256), 0, stream>>>(
        XF, M0F, KFF, WTF, WTH, KFT, SIG, FRHO, M0, out);
}

// Round 8
// 354.178 us; speedup vs baseline: 1.2189x; 1.0412x over previous
//
#include <hip/hip_runtime.h>
#include <cmath>

#define BB 8
#define SS 8192
#define DD 384
#define CH 64
#define NC 128
#define FB 49152   // fragment-linear block per batch

typedef _Float16 h8_t __attribute__((ext_vector_type(8)));
typedef _Float16 h4_t __attribute__((ext_vector_type(4)));
typedef float f32x4 __attribute__((ext_vector_type(4)));

#define MFMA __builtin_amdgcn_mfma_f32_16x16x32_f16

// swizzled LDS accessors
#define LDSA(row, colb) (*(const h8_t*)((const char*)As + (size_t)(row) * 768 + (((colb)) ^ ((((row)) & 7) << 4))))
#define LDSS(row, colb) (*(const h8_t*)((const char*)Ss + (size_t)(row) * 256 + (((colb)) ^ ((((row)) & 7) << 4))))
#define LGT(row, colb) (*(const h8_t*)((const char*)GTl + (size_t)(row) * 256 + (((colb)) ^ ((((row)) & 7) << 4))))
#define LTV(row, colb) (*(const h8_t*)((const char*)Tv  + (size_t)(row) * 256 + (((colb)) ^ ((((row)) & 7) << 4))))

// ---------------------------------------------------------------- K1: stats
__global__ __launch_bounds__(512) void k1_stats(
    const float* __restrict__ x, const float* __restrict__ M0,
    const float* __restrict__ eta_raw, const float* __restrict__ alpha_raw,
    const float* __restrict__ gate_w, const float* __restrict__ gate_b,
    _Float16* __restrict__ XF, _Float16* __restrict__ KF,
    _Float16* __restrict__ KFF, _Float16* __restrict__ UFF,
    float* __restrict__ AB, float* __restrict__ TAB,
    float* __restrict__ SKK, _Float16* __restrict__ M0F)
{
    __shared__ _Float16 ch[CH * 392];   // 50176 B
    __shared__ float rinv[CH];
    __shared__ float kmS[DD], uS[DD];
    __shared__ float redg[8], redk[8];
    const int wg = blockIdx.x, tid = threadIdx.x;
    const int b = wg >> 7, n = wg & 127;
    const int lane = tid & 63, wid = tid >> 6;

    if (wg < 64 && tid < 288) {  // M0 -> f16 fragment-linear
        int rl = tid / 48, c = tid % 48, kd = c >> 2, q = c & 3;
        int o = wg * 6 + rl, rt = o >> 4, l15o = o & 15;
        h8_t v;
        for (int i = 0; i < 8; ++i)
            v[i] = (_Float16)M0[(size_t)o * DD + kd * 32 + q * 8 + i];
        *(h8_t*)&M0F[(size_t)(((kd * 24 + rt) * 64 + q * 16 + l15o) << 3)] = v;
    }

    const size_t chunk_off = (size_t)(b * SS + n * CH) * DD;
    const float4* __restrict__ xin = (const float4*)(x + chunk_off);
    h4_t* __restrict__ xf = (h4_t*)(XF + chunk_off);
    for (int i = tid; i < CH * DD / 4; i += 512) {
        float4 v = xin[i];
        int base = i * 4, r = base / DD, c = base % DD;
        h4_t h; h[0] = (_Float16)v.x; h[1] = (_Float16)v.y;
        h[2] = (_Float16)v.z; h[3] = (_Float16)v.w;
        *(h4_t*)&ch[r * 392 + c] = h;
        xf[i] = h;
    }
    __syncthreads();

    for (int r = wid * 8; r < wid * 8 + 8; ++r) {
        float s = 0.f;
        for (int t = 0; t < 6; ++t) {
            float v = (float)ch[r * 392 + lane + 64 * t]; s += v * v;
        }
        for (int off = 32; off; off >>= 1) s += __shfl_xor(s, off);
        if (lane == 0) rinv[r] = 1.f / fmaxf(sqrtf(s), 1e-5f);
    }
    __syncthreads();

    float gpart = 0.f, skkp = 0.f;
    for (int d = tid; d < DD; d += 512) {
        float xa = 0.f, km = 0.f;
        for (int c = 0; c < CH; ++c) {
            float v = (float)ch[c * 392 + d]; xa += v; km += v * rinv[c];
        }
        xa *= (1.f / 64.f); km *= (1.f / 64.f);
        KF[(size_t)(b * NC + n) * DD + d] = (_Float16)km;
        kmS[d] = km; uS[d] = xa - km;
        gpart += km * gate_w[d];
        skkp += km * km;
    }
    for (int off = 32; off; off >>= 1) {
        gpart += __shfl_xor(gpart, off);
        skkp += __shfl_xor(skkp, off);
    }
    if (lane == 0) { redg[wid] = gpart; redk[wid] = skkp; }
    __syncthreads();
    if (tid == 0) {
        float gsum = 0.f, ks = 0.f;
        for (int i = 0; i < 8; ++i) { gsum += redg[i]; ks += redk[i]; }
        float g = 1.f / (1.f + expf(-(gsum + gate_b[0])));
        float eta = 0.2f / (1.f + expf(-eta_raw[0]));
        float alpha = 0.5f + 0.5f / (1.f + expf(-alpha_raw[0]));
        float A = g * alpha + 1.f - g;
        float Bc = g * eta;
        AB[wg * 2 + 0] = A;
        AB[wg * 2 + 1] = Bc;
        TAB[wg] = Bc / A;
        SKK[wg] = ks;
    }
    if (tid < 96) {  // KFF / UFF fragment-linear slivers for row n
        int isU = tid >= 48, c = tid & 47;
        int kd = c >> 2, q = c & 3;
        int rt = n >> 4, l15n = n & 15;
        h8_t v;
        for (int i = 0; i < 8; ++i)
            v[i] = (_Float16)(isU ? uS[kd * 32 + q * 8 + i] : kmS[kd * 32 + q * 8 + i]);
        _Float16* dst = isU ? UFF : KFF;
        *(h8_t*)&dst[(size_t)b * FB + (((kd * 8 + rt) * 64 + q * 16 + l15n) << 3)] = v;
    }
}

// ------------------------------------------------------------- kBIG: gram+V0+chain+what
// per (b,ob): gram GT (in-LDS, recomputed per ob), V0 tile, 2 chain steps, gram HT
// (reuses GT LDS), what-phase -> SVP/SVVP + VTB global. Bitwise-identical to the
// kA -> chain2 -> what pipeline (same f16 rounding points, same MFMA order).
__global__ __launch_bounds__(256) void kBIG(
    const _Float16* __restrict__ KFF, const _Float16* __restrict__ UFF,
    const _Float16* __restrict__ M0F, const float* __restrict__ TAB,
    _Float16* __restrict__ VTB, float* __restrict__ SVP, float* __restrict__ SVVP)
{
    __shared__ _Float16 GTl[128 * 128];  // 32 KB swizzled; holds GT, then HT
    __shared__ _Float16 Tv[128 * 128];   // 32 KB swizzled; V0 -> VTA -> VTB ([o][j])
    const int b = blockIdx.x / 3, ob = blockIdx.x % 3;
    const int tid = threadIdx.x, lane = tid & 63, w = tid >> 6;
    const int q = lane >> 4, l15 = lane & 15;

    // ---- G1: GT = mask(tau * K@U^T) -> GTl ----
    {
        f32x4 acc[2][8];
        for (int mt = 0; mt < 2; ++mt)
            for (int nt = 0; nt < 8; ++nt) acc[mt][nt] = (f32x4){0.f, 0.f, 0.f, 0.f};
        for (int kd = 0; kd < 12; ++kd) {
            h8_t af[2];
            for (int mt = 0; mt < 2; ++mt)
                af[mt] = *(const h8_t*)&KFF[(size_t)b * FB + (((kd * 8 + w * 2 + mt) * 64 + lane) << 3)];
            h8_t bf[8];
            for (int nt = 0; nt < 8; ++nt)
                bf[nt] = *(const h8_t*)&UFF[(size_t)b * FB + (((kd * 8 + nt) * 64 + lane) << 3)];
            for (int mt = 0; mt < 2; ++mt)
                for (int nt = 0; nt < 8; ++nt)
                    acc[mt][nt] = MFMA(af[mt], bf[nt], acc[mt][nt], 0, 0, 0);
        }
        for (int mt = 0; mt < 2; ++mt)
            for (int nt = 0; nt < 8; ++nt)
                for (int r = 0; r < 4; ++r) {
                    int j = w * 32 + mt * 16 + q * 4 + r;
                    int nn = nt * 16 + l15;
                    float v = (j < nn) ? TAB[b * NC + j] * acc[mt][nt][r] : 0.f;
                    *(_Float16*)((char*)GTl + nn * 256 + ((j * 2) ^ ((nn & 7) << 4))) = (_Float16)v;
                }
    }

    // ---- V0 tile: v0 = U @ M0^T (cols ob) ; f16(v0) -> Tv transposed ----
    f32x4 v0[2][8];
    for (int mt = 0; mt < 2; ++mt)
        for (int ot = 0; ot < 8; ++ot) v0[mt][ot] = (f32x4){0.f, 0.f, 0.f, 0.f};
    for (int kd = 0; kd < 12; ++kd) {
        h8_t af[2];
        for (int mt = 0; mt < 2; ++mt)
            af[mt] = *(const h8_t*)&UFF[(size_t)b * FB + (((kd * 8 + w * 2 + mt) * 64 + lane) << 3)];
        h8_t bf[8];
        for (int ot = 0; ot < 8; ++ot)
            bf[ot] = *(const h8_t*)&M0F[(size_t)(((kd * 24 + ob * 8 + ot) * 64 + lane) << 3)];
        for (int mt = 0; mt < 2; ++mt)
            for (int ot = 0; ot < 8; ++ot)
                v0[mt][ot] = MFMA(af[mt], bf[ot], v0[mt][ot], 0, 0, 0);
    }
    for (int mt = 0; mt < 2; ++mt)
        for (int ot = 0; ot < 8; ++ot)
            for (int r = 0; r < 4; ++r) {
                int nn = w * 32 + mt * 16 + q * 4 + r;
                int o = ot * 16 + l15;
                *(_Float16*)((char*)Tv + o * 256 + ((nn * 2) ^ ((o & 7) << 4))) =
                    (_Float16)v0[mt][ot][r];
            }
    __syncthreads();

    // ---- chain steps: Tv <- f16(f32(f16(v0)) + GT@Tv), twice ----
    for (int step = 0; step < 2; ++step) {
        f32x4 a2[2][8];
        for (int mt = 0; mt < 2; ++mt)
            for (int ot = 0; ot < 8; ++ot) a2[mt][ot] = (f32x4){0.f, 0.f, 0.f, 0.f};
        for (int kd = 0; kd < 4; ++kd) {
            h8_t af[2];
            for (int mt = 0; mt < 2; ++mt)
                af[mt] = LGT(w * 32 + mt * 16 + l15, kd * 64 + q * 16);
            h8_t bf[8];
            for (int ot = 0; ot < 8; ++ot)
                bf[ot] = LTV(ot * 16 + l15, kd * 64 + q * 16);
            for (int mt = 0; mt < 2; ++mt)
                for (int ot = 0; ot < 8; ++ot)
                    a2[mt][ot] = MFMA(af[mt], bf[ot], a2[mt][ot], 0, 0, 0);
        }
        __syncthreads();  // all GTl/Tv reads done before overwrite
        for (int mt = 0; mt < 2; ++mt)
            for (int ot = 0; ot < 8; ++ot)
                for (int r = 0; r < 4; ++r) {
                    int nn = w * 32 + mt * 16 + q * 4 + r;
                    int o = ot * 16 + l15;
                    _Float16 vh = (_Float16)((float)(_Float16)v0[mt][ot][r] + a2[mt][ot][r]);
                    *(_Float16*)((char*)Tv + o * 256 + ((nn * 2) ^ ((o & 7) << 4))) = vh;
                    if (step == 1)
                        VTB[((size_t)b * NC + nn) * DD + ob * 128 + o] = vh;
                }
        if (step == 0) __syncthreads();
    }

    // ---- G2: HT = mask(tau * K@K^T) -> GTl (reuse; GT reads are done) ----
    {
        f32x4 acc[2][8];
        for (int mt = 0; mt < 2; ++mt)
            for (int nt = 0; nt < 8; ++nt) acc[mt][nt] = (f32x4){0.f, 0.f, 0.f, 0.f};
        for (int kd = 0; kd < 12; ++kd) {
            h8_t af[2];
            for (int mt = 0; mt < 2; ++mt)
                af[mt] = *(const h8_t*)&KFF[(size_t)b * FB + (((kd * 8 + w * 2 + mt) * 64 + lane) << 3)];
            h8_t bf[8];
            for (int nt = 0; nt < 8; ++nt)
                bf[nt] = *(const h8_t*)&KFF[(size_t)b * FB + (((kd * 8 + nt) * 64 + lane) << 3)];
            for (int mt = 0; mt < 2; ++mt)
                for (int nt = 0; nt < 8; ++nt)
                    acc[mt][nt] = MFMA(af[mt], bf[nt], acc[mt][nt], 0, 0, 0);
        }
        for (int mt = 0; mt < 2; ++mt)
            for (int nt = 0; nt < 8; ++nt)
                for (int r = 0; r < 4; ++r) {
                    int j = w * 32 + mt * 16 + q * 4 + r;
                    int nn = nt * 16 + l15;
                    float v = (j < nn) ? TAB[b * NC + j] * acc[mt][nt][r] : 0.f;
                    *(_Float16*)((char*)GTl + nn * 256 + ((j * 2) ^ ((nn & 7) << 4))) = (_Float16)v;
                }
    }
    __syncthreads();

    // ---- what: accW = K@M0^T + HT@Vhat; sv/svv partials ----
    f32x4 aw[2][8];
    for (int mt = 0; mt < 2; ++mt)
        for (int ot = 0; ot < 8; ++ot) aw[mt][ot] = (f32x4){0.f, 0.f, 0.f, 0.f};
    for (int kd = 0; kd < 12; ++kd) {
        h8_t af[2];
        for (int mt = 0; mt < 2; ++mt)
            af[mt] = *(const h8_t*)&KFF[(size_t)b * FB + (((kd * 8 + w * 2 + mt) * 64 + lane) << 3)];
        h8_t bf[8];
        for (int ot = 0; ot < 8; ++ot)
            bf[ot] = *(const h8_t*)&M0F[(size_t)(((kd * 24 + ob * 8 + ot) * 64 + lane) << 3)];
        for (int mt = 0; mt < 2; ++mt)
            for (int ot = 0; ot < 8; ++ot)
                aw[mt][ot] = MFMA(af[mt], bf[ot], aw[mt][ot], 0, 0, 0);
    }
    for (int kd = 0; kd < 4; ++kd) {
        h8_t af[2];
        for (int mt = 0; mt < 2; ++mt)
            af[mt] = LGT(w * 32 + mt * 16 + l15, kd * 64 + q * 16);
        h8_t bf[8];
        for (int ot = 0; ot < 8; ++ot)
            bf[ot] = LTV(ot * 16 + l15, kd * 64 + q * 16);
        for (int mt = 0; mt < 2; ++mt)
            for (int ot = 0; ot < 8; ++ot)
                aw[mt][ot] = MFMA(af[mt], bf[ot], aw[mt][ot], 0, 0, 0);
    }
    for (int mt = 0; mt < 2; ++mt)
        for (int r = 0; r < 4; ++r) {
            int nn = w * 32 + mt * 16 + q * 4 + r;
            float sv = 0.f, svv = 0.f;
            for (int ot = 0; ot < 8; ++ot) {
                int o = ot * 16 + l15;
                float vh = (float)*(const _Float16*)((const char*)Tv + o * 256 +
                                                     ((nn * 2) ^ ((o & 7) << 4)));
                sv += aw[mt][ot][r] * vh;
                svv += vh * vh;
            }
            sv += __shfl_xor(sv, 1); svv += __shfl_xor(svv, 1);
            sv += __shfl_xor(sv, 2); svv += __shfl_xor(svv, 2);
            sv += __shfl_xor(sv, 4); svv += __shfl_xor(svv, 4);
            sv += __shfl_xor(sv, 8); svv += __shfl_xor(svv, 8);
            if (l15 == 0) {
                SVP[(b * 3 + ob) * NC + nn] = sv;
                SVVP[(b * 3 + ob) * NC + nn] = svv;
            }
        }
}

// ---------------------------------------------- kTS: transposes (0..47) + scan (48..55)
__global__ __launch_bounds__(256) void kTS(
    const _Float16* __restrict__ VHT, const _Float16* __restrict__ KF,
    const float* __restrict__ TAB, const float* __restrict__ M0,
    const float* __restrict__ AB, const float* __restrict__ SKK,
    const float* __restrict__ SVP, const float* __restrict__ SVVP,
    _Float16* __restrict__ WTH, _Float16* __restrict__ KFT,
    _Float16* __restrict__ WTF,
    float* __restrict__ SIG, float* __restrict__ FRHO)
{
    const int tid = threadIdx.x;
    if (blockIdx.x < 48) {
        __shared__ _Float16 T[128 * 72];
        const int b = blockIdx.x / 6, ob = blockIdx.x % 6;
        for (int pass = 0; pass < 2; ++pass) {
            const _Float16* Src = pass ? KF : VHT;
            _Float16* Dst = pass ? KFT : WTH;
            if (pass) __syncthreads();
            for (int pp = 0; pp < 4; ++pp) {
                int j = pp * 32 + (tid >> 3), oo = (tid & 7) * 8;
                *(h8_t*)&T[j * 72 + oo] =
                    *(const h8_t*)&Src[((size_t)b * NC + j) * DD + ob * 64 + oo];
            }
            __syncthreads();
            for (int c = 0; c < 4; ++c) {
                int idx2 = c * 256 + tid;
                int ol = idx2 >> 4, jc = (idx2 & 15) * 8;
                h8_t v;
                for (int i = 0; i < 8; ++i) {
                    float t = (float)T[(jc + i) * 72 + ol];
                    if (!pass) t *= TAB[b * NC + jc + i];
                    v[i] = (_Float16)t;
                }
                *(h8_t*)&Dst[((size_t)b * DD + ob * 64 + ol) * NC + jc] = v;
                if (!pass) {
                    int o = ob * 64 + ol, rt = o >> 4, l15o = o & 15;
                    int kb = jc >> 5, qq = (jc >> 3) & 3;
                    *(h8_t*)&WTF[(size_t)b * FB + (((kb * 24 + rt) * 64 + qq * 16 + l15o) << 3)] = v;
                }
            }
        }
    } else {
        __shared__ float sA[NC], sB[NC], sSV[NC], sVV[NC], sKK[NC], sig_s[NC];
        __shared__ float red[4];
        const int b = blockIdx.x - 48;
        for (int i = tid; i < NC; i += 256) {
            sA[i] = AB[(b * NC + i) * 2];
            sB[i] = AB[(b * NC + i) * 2 + 1];
            sSV[i] = SVP[(b * 3 + 0) * NC + i] + SVP[(b * 3 + 1) * NC + i]
                     + SVP[(b * 3 + 2) * NC + i];
            sVV[i] = SVVP[(b * 3 + 0) * NC + i] + SVVP[(b * 3 + 1) * NC + i]
                     + SVVP[(b * 3 + 2) * NC + i];
            sKK[i] = SKK[b * NC + i];
        }
        float p = 0.f;
        const float4* m4 = (const float4*)M0;
        for (int i = tid; i < DD * DD / 4; i += 256) {
            float4 v = m4[i];
            p += v.x * v.x + v.y * v.y + v.z * v.z + v.w * v.w;
        }
        for (int off = 32; off; off >>= 1) p += __shfl_xor(p, off);
        if ((tid & 63) == 0) red[tid >> 6] = p;
        __syncthreads();
        if (tid == 0) {
            float phi2 = red[0] + red[1] + red[2] + red[3];
            float an = 1.f, rho = 1.f;
            for (int n = 0; n < NC; ++n) {
                float A = sA[n], Bc = sB[n];
                sig_s[n] = rho * an;
                float a2 = an * an;
                phi2 = A * A * phi2 + 2.f * A * Bc * a2 * sSV[n]
                       + Bc * Bc * a2 * sVV[n] * sKK[n];
                float s = fminf(30.f / (rho * sqrtf(phi2) + 1e-6f), 1.f);
                rho *= s; an *= A;
            }
            FRHO[b] = rho * an;
        }
        __syncthreads();
        for (int i = tid; i < NC; i += 256) SIG[b * NC + i] = sig_s[i];
    }
}

// ------------------------------------------------------------ K4: fused score+output
__global__ __launch_bounds__(256, 2) void k4_out(
    const _Float16* __restrict__ XF, const _Float16* __restrict__ M0F,
    const _Float16* __restrict__ KFF, const _Float16* __restrict__ WTF,
    const _Float16* __restrict__ WTH, const _Float16* __restrict__ KFT,
    const float* __restrict__ SIG, const float* __restrict__ FRHO,
    const float* __restrict__ M0, float* __restrict__ out)
{
    const int tid = threadIdx.x, lane = tid & 63, w = tid >> 6;
    const int q = lane >> 4, l15 = lane & 15;

    if (blockIdx.x >= BB * NC) {  // M_fin tail: 96 WGs
        const int tw = blockIdx.x - BB * NC;
        const int b = tw / 12, sub = tw % 12;
        const int obk = sub >> 1, dh = sub & 1;
        const int o_t = obk * 64 + w * 16;
        f32x4 acc[12];
        for (int dt = 0; dt < 12; ++dt) acc[dt] = (f32x4){0.f, 0.f, 0.f, 0.f};
        for (int kd = 0; kd < 4; ++kd) {
            h8_t af = *(const h8_t*)&WTH[((size_t)b * DD + o_t + l15) * NC + kd * 32 + q * 8];
            for (int dt = 0; dt < 12; ++dt) {
                int d = dh * 192 + dt * 16 + l15;
                h8_t bf = *(const h8_t*)&KFT[((size_t)b * DD + d) * NC + kd * 32 + q * 8];
                acc[dt] = MFMA(af, bf, acc[dt], 0, 0, 0);
            }
        }
        float fr = FRHO[b];
        float* dst = out + (size_t)BB * SS * DD;
        for (int dt = 0; dt < 12; ++dt)
            for (int r = 0; r < 4; ++r) {
                int o = o_t + q * 4 + r, d = dh * 192 + dt * 16 + l15;
                dst[((size_t)b * DD + o) * DD + d] =
                    fr * (M0[(size_t)o * DD + d] + acc[dt][r]);
            }
        return;
    }

    __shared__ _Float16 As[CH * DD];   // 48 KB
    __shared__ _Float16 Ss[CH * NC];   // 16 KB

    const int b = blockIdx.x >> 7, n = blockIdx.x & 127;
    const size_t chunk_off = (size_t)(b * SS + n * CH) * DD;
    const int nb = (n + 31) >> 5;

    // ---- stage chunk: contiguous 1KB bursts, swizzled LDS ----
    {
        const char* src = (const char*)(XF + chunk_off);
        char* dstb = (char*)As;
        for (int i = 0; i < 12; ++i) {
            int P = (w * 12 + i) * 1024 + lane * 16;
            int row = P / 768;
            int colS = P - row * 768;
            int colG = colS ^ ((row & 7) << 4);
            *(h8_t*)(dstb + P) = *(const h8_t*)(src + row * 768 + colG);
        }
    }
    __syncthreads();

    // ---- phase A: S-tile = chunk @ K^T -> LDS ----
    if (w * 32 < n) {
        f32x4 accS[4][2];
        for (int mi = 0; mi < 4; ++mi)
            for (int nj = 0; nj < 2; ++nj) accS[mi][nj] = (f32x4){0.f, 0.f, 0.f, 0.f};
        for (int kd = 0; kd < 12; ++kd) {
            h8_t af[4];
            for (int mi = 0; mi < 4; ++mi)
                af[mi] = LDSA(mi * 16 + l15, kd * 64 + q * 16);
            h8_t bfk[2];
            for (int nj = 0; nj < 2; ++nj)
                bfk[nj] = *(const h8_t*)&KFF[(size_t)b * FB + (((kd * 8 + w * 2 + nj) * 64 + lane) << 3)];
            for (int mi = 0; mi < 4; ++mi)
                for (int nj = 0; nj < 2; ++nj)
                    accS[mi][nj] = MFMA(af[mi], bfk[nj], accS[mi][nj], 0, 0, 0);
        }
        for (int mi = 0; mi < 4; ++mi)
            for (int nj = 0; nj < 2; ++nj)
                for (int r = 0; r < 4; ++r) {
                    int c = mi * 16 + q * 4 + r, j = w * 32 + nj * 16 + l15;
                    _Float16 sv = (_Float16)((j < n) ? accS[mi][nj][r] : 0.f);
                    *(_Float16*)((char*)Ss + c * 256 + ((j * 2) ^ ((c & 7) << 4))) = sv;
                }
    }
    __syncthreads();

    // ---- phase C: out = chunk @ M0^T + S @ WTH^T ----
    f32x4 acc[4][6];
    for (int mi = 0; mi < 4; ++mi)
        for (int nj = 0; nj < 6; ++nj) acc[mi][nj] = (f32x4){0.f, 0.f, 0.f, 0.f};

    for (int kd = 0; kd < 12; ++kd) {  // term1: chunk @ M0^T
        h8_t af[4];
        for (int mi = 0; mi < 4; ++mi)
            af[mi] = LDSA(mi * 16 + l15, kd * 64 + q * 16);
        h8_t bf[6];
        for (int nj = 0; nj < 6; ++nj)
            bf[nj] = *(const h8_t*)&M0F[(size_t)(((kd * 24 + w * 6 + nj) * 64 + lane) << 3)];
        for (int mi = 0; mi < 4; ++mi)
            for (int nj = 0; nj < 6; ++nj)
                acc[mi][nj] = MFMA(af[mi], bf[nj], acc[mi][nj], 0, 0, 0);
    }

    for (int kb = 0; kb < nb; ++kb) {  // + S @ WTH^T
        h8_t af[4];
        for (int mi = 0; mi < 4; ++mi)
            af[mi] = LDSS(mi * 16 + l15, kb * 64 + q * 16);
        h8_t bf[6];
        for (int nj = 0; nj < 6; ++nj)
            bf[nj] = *(const h8_t*)&WTF[(size_t)b * FB + (((kb * 24 + w * 6 + nj) * 64 + lane) << 3)];
        for (int mi = 0; mi < 4; ++mi)
            for (int nj = 0; nj < 6; ++nj)
                acc[mi][nj] = MFMA(af[mi], bf[nj], acc[mi][nj], 0, 0, 0);
    }

    const float sg = SIG[b * NC + n];
    for (int mi = 0; mi < 4; ++mi)
        for (int nj = 0; nj < 6; ++nj)
            for (int r = 0; r < 4; ++r) {
                int c = mi * 16 + q * 4 + r, o = w * 96 + nj * 16 + l15;
                out[chunk_off + (size_t)c * DD + o] = sg * acc[mi][nj][r];
            }
}

// ---------------------------------------------------------------- launch
extern "C" void kernel_launch(void* const* d_in, const int* in_sizes, int n_in,
                              void* d_out, int out_size, void* d_ws, size_t ws_size,
                              hipStream_t stream) {
    (void)in_sizes; (void)n_in; (void)out_size; (void)ws_size;
    const float* x         = (const float*)d_in[0];
    const float* M0        = (const float*)d_in[1];
    const float* eta_raw   = (const float*)d_in[2];
    const float* alpha_raw = (const float*)d_in[3];
    const float* gate_w    = (const float*)d_in[4];
    const float* gate_b    = (const float*)d_in[5];
    float* out = (float*)d_out;
    char* ws = (char*)d_ws;

    _Float16* XF  = (_Float16*)(ws);                 // 50,331,648
    _Float16* KF  = (_Float16*)(ws + 51118080);      //    786,432
    _Float16* VTB = (_Float16*)(ws + 54296576);      //    786,432
    _Float16* WTH = (_Float16*)(ws + 55083008);      //    786,432
    _Float16* KFT = (_Float16*)(ws + 55869440);      //    786,432
    _Float16* M0F = (_Float16*)(ws + 56655872);      //    294,912
    _Float16* KFF = (_Float16*)(ws + 56950784);      //    786,432
    _Float16* UFF = (_Float16*)(ws + 57737216);      //    786,432
    _Float16* WTF = (_Float16*)(ws + 58523648);      //    786,432
    float*    AB  = (float*)(ws + 73433088);         //      8,192
    float*    TAB = (float*)(ws + 73441280);         //      4,096
    float*    SKK = (float*)(ws + 73445376);         //      4,096
    float*    SVP = (float*)(ws + 73449472);         //     12,288
    float*    SVVP= (float*)(ws + 73461760);         //     12,288
    float*    SIG = (float*)(ws + 73474048);         //      4,096
    float*    FRHO= (float*)(ws + 73478144);         //        256

    k1_stats<<<dim3(BB * NC), dim3(512), 0, stream>>>(
        x, M0, eta_raw, alpha_raw, gate_w, gate_b, XF, KF, KFF, UFF,
        AB, TAB, SKK, M0F);
    kBIG<<<dim3(BB * 3), dim3(256), 0, stream>>>(
        KFF, UFF, M0F, TAB, VTB, SVP, SVVP);
    kTS<<<dim3(56), dim3(256), 0, stream>>>(
        VTB, KF, TAB, M0, AB, SKK, SVP, SVVP, WTH, KFT, WTF, SIG, FRHO);
    k4_out<<<dim3(BB * NC + 96), dim3(256), 0, stream>>>(
        XF, M0F, KFF, WTF, WTH, KFT, SIG, FRHO, M0, out);
}